// Round 4
// baseline (328.058 us; speedup 1.0000x reference)
//
#include <hip/hip_runtime.h>
#include <hip/hip_bf16.h>
#include <math.h>

#define N_ENT   100000
#define DIM     128
#define N_EDGES 1600000
#define BATCH   8192
#define EPS     1e-5f
#define CAP     128          // max neighbors stored per needed node (Poisson(16) tail ~0)

// ---------------- ws layout (4-byte elements) ----------------
// zero region: [0, 8720)
#define WS_COLSUM    0          // f[128]
#define WS_COLSUMSQ  128        // f[128]
#define WS_SCALE     256        // f[128]
#define WS_SHIFT     384        // f[128]
#define WS_COUNT     512        // i[16] (count in [0])
#define WS_BCOUNT    528        // i[8192] per-slot edge count (== degree)
#define WS_ZERO_INTS 8720
// 0xFF region:
#define WS_SLOTOF    8720       // i[100000]  (-1 = unneeded, -2 = marked, >=0 = slot)
// data:
#define WS_BUCKET    108720     // i[8192*128]  (16B aligned)
#define WS_HCOMP     1157296    // f[8192*128]  (16B aligned)

// K1: per-column sum/sumsq of E, float4 lanes.
// t = rs*32 + cg : cg = float4 column group (0..31), rs = row slice (0..7).
__global__ __launch_bounds__(256) void stats_kernel(const float4* __restrict__ E4,
                                                    float* __restrict__ colsum,
                                                    float* __restrict__ colsumsq) {
    int t = threadIdx.x;
    int cg = t & 31;
    int rs = t >> 5;
    float sx = 0.f, sy = 0.f, sz = 0.f, sw = 0.f;
    float qx = 0.f, qy = 0.f, qz = 0.f, qw = 0.f;
    for (int r = blockIdx.x * 8 + rs; r < N_ENT; r += gridDim.x * 8) {
        float4 v = E4[(size_t)r * 32 + cg];
        sx += v.x; sy += v.y; sz += v.z; sw += v.w;
        qx += v.x * v.x; qy += v.y * v.y; qz += v.z * v.z; qw += v.w * v.w;
    }
    __shared__ float sh[8 * 256];   // plane j (4 sum + 4 sq), thread t
    sh[0 * 256 + t] = sx; sh[1 * 256 + t] = sy;
    sh[2 * 256 + t] = sz; sh[3 * 256 + t] = sw;
    sh[4 * 256 + t] = qx; sh[5 * 256 + t] = qy;
    sh[6 * 256 + t] = qz; sh[7 * 256 + t] = qw;
    __syncthreads();
    for (int o = 128; o >= 32; o >>= 1) {
        if (t < o) {
#pragma unroll
            for (int j = 0; j < 8; ++j) sh[j * 256 + t] += sh[j * 256 + t + o];
        }
        __syncthreads();
    }
    if (t < 32) {
        atomicAdd(&colsum[t * 4 + 0], sh[0 * 256 + t]);
        atomicAdd(&colsum[t * 4 + 1], sh[1 * 256 + t]);
        atomicAdd(&colsum[t * 4 + 2], sh[2 * 256 + t]);
        atomicAdd(&colsum[t * 4 + 3], sh[3 * 256 + t]);
        atomicAdd(&colsumsq[t * 4 + 0], sh[4 * 256 + t]);
        atomicAdd(&colsumsq[t * 4 + 1], sh[5 * 256 + t]);
        atomicAdd(&colsumsq[t * 4 + 2], sh[6 * 256 + t]);
        atomicAdd(&colsumsq[t * 4 + 3], sh[7 * 256 + t]);
    }
}

// K2: fold batchnorm into per-column scale/shift.
__global__ __launch_bounds__(128) void finalize_kernel(const float* __restrict__ colsum,
                                                       const float* __restrict__ colsumsq,
                                                       const float* __restrict__ gamma,
                                                       const float* __restrict__ beta,
                                                       float* __restrict__ scale,
                                                       float* __restrict__ shift) {
    int c = threadIdx.x;
    const float invn = 1.0f / (float)N_ENT;
    float mu = colsum[c] * invn;
    float var = colsumsq[c] * invn - mu * mu;
    float rs = rsqrtf(var + EPS);
    float sc = gamma[c] * rs;
    scale[c] = sc;
    shift[c] = beta[c] - mu * sc;
}

// K3: mark needed nodes (idempotent stores; slot_of pre-filled with -1).
__global__ __launch_bounds__(256) void mark_kernel(const int* __restrict__ neighbor,
                                                   int* __restrict__ slot_of) {
    int b = blockIdx.x * 256 + threadIdx.x;
    if (b < BATCH) slot_of[neighbor[b]] = -2;
}

// K4: assign compact slots to marked nodes.
__global__ __launch_bounds__(256) void compact_kernel(int* __restrict__ slot_of,
                                                      int* __restrict__ count) {
    int n = blockIdx.x * 256 + threadIdx.x;
    if (n < N_ENT && slot_of[n] == -2) {
        slot_of[n] = atomicAdd(count, 1);   // wave-aggregated by compiler
    }
}

// K5: single edge pass, int4-vectorized — bucket sources of needed-dst edges.
__global__ __launch_bounds__(256) void edge_bucket_kernel(const int4* __restrict__ src4,
                                                          const int4* __restrict__ dst4,
                                                          const int* __restrict__ slot_of,
                                                          int* __restrict__ bcount,
                                                          int* __restrict__ bucket) {
    const int n4 = N_EDGES / 4;   // 400000, exact
    for (int e = blockIdx.x * blockDim.x + threadIdx.x; e < n4;
         e += gridDim.x * blockDim.x) {
        int4 d = dst4[e];
        int4 s = src4[e];
        int sl0 = slot_of[d.x];
        int sl1 = slot_of[d.y];
        int sl2 = slot_of[d.z];
        int sl3 = slot_of[d.w];
        if (sl0 >= 0) { int p = atomicAdd(&bcount[sl0], 1); if (p < CAP) bucket[sl0 * CAP + p] = s.x; }
        if (sl1 >= 0) { int p = atomicAdd(&bcount[sl1], 1); if (p < CAP) bucket[sl1 * CAP + p] = s.y; }
        if (sl2 >= 0) { int p = atomicAdd(&bcount[sl2], 1); if (p < CAP) bucket[sl2 * CAP + p] = s.z; }
        if (sl3 >= 0) { int p = atomicAdd(&bcount[sl3], 1); if (p < CAP) bucket[sl3 * CAP + p] = s.w; }
    }
}

// K6: gather-aggregate per needed slot. One 64-lane wave per slot.
// hcomp[slot] = (scale * sum(E[src]) + deg*shift) / max(deg,1)
__global__ __launch_bounds__(256) void gather_kernel(const float4* __restrict__ E4,
                                                     const int* __restrict__ count,
                                                     const int* __restrict__ bcount,
                                                     const int* __restrict__ bucket,
                                                     const float4* __restrict__ scale4,
                                                     const float4* __restrict__ shift4,
                                                     float* __restrict__ hcomp) {
    int t = threadIdx.x;
    int slot = blockIdx.x * 4 + (t >> 6);
    int U = count[0];
    if (slot >= U) return;
    int lane = t & 63;
    int q = lane & 31;
    int sub = lane >> 5;
    int dg = bcount[slot];
    int m = dg < CAP ? dg : CAP;
    float ax = 0.f, ay = 0.f, az = 0.f, aw = 0.f;
    for (int i = sub; i < m; i += 2) {
        int s = bucket[slot * CAP + i];
        float4 ev = E4[(size_t)s * 32 + q];
        ax += ev.x; ay += ev.y; az += ev.z; aw += ev.w;
    }
    ax += __shfl_down(ax, 32);
    ay += __shfl_down(ay, 32);
    az += __shfl_down(az, 32);
    aw += __shfl_down(aw, 32);
    if (sub == 0) {
        float fdg = (float)dg;
        float rd = 1.0f / fmaxf(fdg, 1.0f);
        float4 sc = scale4[q];
        float4 sf = shift4[q];
        float4 o;
        o.x = (ax * sc.x + fdg * sf.x) * rd;
        o.y = (ay * sc.y + fdg * sf.y) * rd;
        o.z = (az * sc.z + fdg * sf.z) * rd;
        o.w = (aw * sc.w + fdg * sf.w) * rd;
        ((float4*)(hcomp + (size_t)slot * DIM))[q] = o;
    }
}

// K7: h2 = relu(hcomp @ W + b), in-place. 32 rows/block.
__global__ __launch_bounds__(256) void gnn_gemm_kernel(float* __restrict__ hcomp,
                                                       const float* __restrict__ W,
                                                       const float* __restrict__ bias) {
    __shared__ float A_s[32 * 128];
    int t = threadIdx.x;
    int rowbase = blockIdx.x * 32;

    const float4* src4 = (const float4*)(hcomp + (size_t)rowbase * DIM);
#pragma unroll
    for (int i = 0; i < 4; ++i) {
        int f4 = t + i * 256;
        ((float4*)A_s)[f4] = src4[f4];
    }
    __syncthreads();

    int cg = t & 31;
    int rg = t >> 5;
    int r0 = rg * 4;
    float acc[4][4] = {{0.f}};
    const float4* W4 = (const float4*)W;
#pragma unroll 4
    for (int k = 0; k < 128; ++k) {
        float4 wv = W4[k * 32 + cg];
#pragma unroll
        for (int i = 0; i < 4; ++i) {
            float a = A_s[(r0 + i) * 128 + k];
            acc[i][0] += a * wv.x;
            acc[i][1] += a * wv.y;
            acc[i][2] += a * wv.z;
            acc[i][3] += a * wv.w;
        }
    }
    float4 bv = ((const float4*)bias)[cg];
#pragma unroll
    for (int i = 0; i < 4; ++i) {
        float4 o;
        o.x = fmaxf(acc[i][0] + bv.x, 0.f);
        o.y = fmaxf(acc[i][1] + bv.y, 0.f);
        o.z = fmaxf(acc[i][2] + bv.z, 0.f);
        o.w = fmaxf(acc[i][3] + bv.w, 0.f);
        ((float4*)(hcomp + (size_t)(rowbase + r0 + i) * DIM))[cg] = o;
    }
}

// K8: heads. One 64-thread wave per batch element; u via slot_of indirection.
__global__ __launch_bounds__(64) void heads_kernel(const float* __restrict__ hcomp,
                                                   const int* __restrict__ slot_of,
                                                   const int* __restrict__ neighbor,
                                                   const float* __restrict__ W_g,
                                                   const float* __restrict__ b_g,
                                                   const float* __restrict__ W_age,
                                                   const float* __restrict__ b_age,
                                                   const float* __restrict__ W_occ,
                                                   const float* __restrict__ b_occ,
                                                   float* __restrict__ out_age,
                                                   float* __restrict__ out_gender,
                                                   float* __restrict__ out_occ) {
    int b = blockIdx.x;
    int lane = threadIdx.x;
    int slot = slot_of[neighbor[b]];
    __shared__ float u[DIM];
    ((float2*)u)[lane] = ((const float2*)(hcomp + (size_t)slot * DIM))[lane];
    __syncthreads();
    if (lane < 7) {
        float acc = b_age[lane];
        for (int d = 0; d < DIM; ++d) acc += u[d] * W_age[d * 7 + lane];
        out_age[b * 7 + lane] = acc;
    } else if (lane < 28) {
        int c = lane - 7;
        float acc = b_occ[c];
        for (int d = 0; d < DIM; ++d) acc += u[d] * W_occ[d * 21 + c];
        out_occ[b * 21 + c] = acc;
    } else if (lane == 28) {
        float acc = b_g[0];
        for (int d = 0; d < DIM; ++d) acc += u[d] * W_g[d];
        out_gender[b] = acc;
    }
}

// K9: BCE-with-logits mean.
__global__ __launch_bounds__(256) void loss_kernel(const float* __restrict__ gender_pred,
                                                   const int* __restrict__ gender,
                                                   float* __restrict__ out_loss) {
    int t = threadIdx.x;
    float s = 0.f;
    for (int i = t; i < BATCH; i += 256) {
        float x = gender_pred[i];
        float z = (float)gender[i];
        s += fmaxf(x, 0.f) - x * z + log1pf(expf(-fabsf(x)));
    }
    __shared__ float sh[256];
    sh[t] = s;
    __syncthreads();
    for (int o = 128; o > 0; o >>= 1) {
        if (t < o) sh[t] += sh[t + o];
        __syncthreads();
    }
    if (t == 0) out_loss[0] = sh[0] / (float)BATCH;
}

extern "C" void kernel_launch(void* const* d_in, const int* in_sizes, int n_in,
                              void* d_out, int out_size, void* d_ws, size_t ws_size,
                              hipStream_t stream) {
    const float* E      = (const float*)d_in[0];
    const float* gamma  = (const float*)d_in[1];
    const float* beta   = (const float*)d_in[2];
    const float* W_gnn  = (const float*)d_in[3];
    const float* b_gnn  = (const float*)d_in[4];
    const float* W_g    = (const float*)d_in[5];
    const float* b_g    = (const float*)d_in[6];
    const float* W_age  = (const float*)d_in[7];
    const float* b_age  = (const float*)d_in[8];
    const float* W_occ  = (const float*)d_in[9];
    const float* b_occ  = (const float*)d_in[10];
    const int*   src    = (const int*)d_in[11];
    const int*   dst    = (const int*)d_in[12];
    const int*   neigh  = (const int*)d_in[13];
    const int*   gender = (const int*)d_in[14];

    float* ws       = (float*)d_ws;
    int*   wsi      = (int*)d_ws;
    float* colsum   = ws + WS_COLSUM;
    float* colsumsq = ws + WS_COLSUMSQ;
    float* scale    = ws + WS_SCALE;
    float* shift    = ws + WS_SHIFT;
    int*   count    = wsi + WS_COUNT;
    int*   bcount   = wsi + WS_BCOUNT;
    int*   slot_of  = wsi + WS_SLOTOF;
    int*   bucket   = wsi + WS_BUCKET;
    float* hcomp    = ws + WS_HCOMP;

    float* out       = (float*)d_out;
    float* out_loss  = out;                         // [1]
    float* out_age   = out + 1;                     // [8192,7]
    float* out_gen   = out + 1 + BATCH * 7;         // [8192]
    float* out_occ   = out + 1 + BATCH * 7 + BATCH; // [8192,21]

    // init: zeros for accumulators, 0xFF (-1) for slot_of
    hipMemsetAsync(d_ws, 0, (size_t)WS_ZERO_INTS * 4, stream);
    hipMemsetAsync((void*)slot_of, 0xFF, (size_t)N_ENT * 4, stream);

    stats_kernel<<<1024, 256, 0, stream>>>((const float4*)E, colsum, colsumsq);
    finalize_kernel<<<1, 128, 0, stream>>>(colsum, colsumsq, gamma, beta, scale, shift);
    mark_kernel<<<BATCH / 256, 256, 0, stream>>>(neigh, slot_of);
    compact_kernel<<<(N_ENT + 255) / 256, 256, 0, stream>>>(slot_of, count);
    edge_bucket_kernel<<<1024, 256, 0, stream>>>((const int4*)src, (const int4*)dst,
                                                 slot_of, bcount, bucket);
    gather_kernel<<<BATCH / 4, 256, 0, stream>>>((const float4*)E, count, bcount, bucket,
                                                 (const float4*)scale, (const float4*)shift,
                                                 hcomp);
    gnn_gemm_kernel<<<BATCH / 32, 256, 0, stream>>>(hcomp, W_gnn, b_gnn);
    heads_kernel<<<BATCH, 64, 0, stream>>>(hcomp, slot_of, neigh, W_g, b_g,
                                           W_age, b_age, W_occ, b_occ,
                                           out_age, out_gen, out_occ);
    loss_kernel<<<1, 256, 0, stream>>>(out_gen, gender, out_loss);
}

// Round 5
// 234.462 us; speedup vs baseline: 1.3992x; 1.3992x over previous
//
#include <hip/hip_runtime.h>
#include <hip/hip_bf16.h>
#include <math.h>

#define N_ENT   100000
#define DIM     128
#define N_EDGES 1600000
#define BATCH   8192
#define EPS     1e-5f
#define CAP     128          // max neighbors stored per needed node (Poisson(16) tail ~0)
#define NSTAT_BLK 512

// ---------------- ws layout (4-byte elements) ----------------
// zero region: [0, 8720)
#define WS_SCALE     256        // f[128]
#define WS_SHIFT     384        // f[128]
#define WS_COUNT     512        // i[16] (count in [0])
#define WS_BCOUNT    528        // i[8192] per-slot edge count (== degree)
#define WS_ZERO_INTS 8720
// 0xFF region:
#define WS_SLOTOF    8720       // i[100000]  (-1 = unneeded, -2 = marked, >=0 = slot)
// data (no init needed):
#define WS_BUCKET    108720     // i[8192*128]  (16B aligned)
#define WS_HCOMP     1157296    // f[8192*128]  (16B aligned)
#define WS_PARTIAL   2205872    // f[512*256]   stats partials

// K1: per-column sum/sumsq of E, float4 lanes, x4-unrolled rows, NO atomics.
// t = rs*32 + cg : cg = float4 column group (0..31), rs = row slice (0..7).
// partial[b*256 + j*32 + t] , planes j: 0-3 sum comps, 4-7 sq comps.
__global__ __launch_bounds__(256) void stats_kernel(const float4* __restrict__ E4,
                                                    float* __restrict__ partial) {
    int t = threadIdx.x;
    int cg = t & 31;
    int rs = t >> 5;
    const int STRIDE = NSTAT_BLK * 8;   // 4096 rows per sweep
    float sx = 0.f, sy = 0.f, sz = 0.f, sw = 0.f;
    float qx = 0.f, qy = 0.f, qz = 0.f, qw = 0.f;
    const float4 z4 = make_float4(0.f, 0.f, 0.f, 0.f);
    for (int r = blockIdx.x * 8 + rs; r < N_ENT; r += 4 * STRIDE) {
        int r1 = r + STRIDE, r2 = r + 2 * STRIDE, r3 = r + 3 * STRIDE;
        float4 v0 = E4[(size_t)r * 32 + cg];
        float4 v1 = (r1 < N_ENT) ? E4[(size_t)r1 * 32 + cg] : z4;
        float4 v2 = (r2 < N_ENT) ? E4[(size_t)r2 * 32 + cg] : z4;
        float4 v3 = (r3 < N_ENT) ? E4[(size_t)r3 * 32 + cg] : z4;
        sx += v0.x + v1.x + v2.x + v3.x;
        sy += v0.y + v1.y + v2.y + v3.y;
        sz += v0.z + v1.z + v2.z + v3.z;
        sw += v0.w + v1.w + v2.w + v3.w;
        qx += v0.x * v0.x + v1.x * v1.x + v2.x * v2.x + v3.x * v3.x;
        qy += v0.y * v0.y + v1.y * v1.y + v2.y * v2.y + v3.y * v3.y;
        qz += v0.z * v0.z + v1.z * v1.z + v2.z * v2.z + v3.z * v3.z;
        qw += v0.w * v0.w + v1.w * v1.w + v2.w * v2.w + v3.w * v3.w;
    }
    __shared__ float sh[8 * 256];
    sh[0 * 256 + t] = sx; sh[1 * 256 + t] = sy;
    sh[2 * 256 + t] = sz; sh[3 * 256 + t] = sw;
    sh[4 * 256 + t] = qx; sh[5 * 256 + t] = qy;
    sh[6 * 256 + t] = qz; sh[7 * 256 + t] = qw;
    __syncthreads();
    for (int o = 128; o >= 32; o >>= 1) {
        if (t < o) {
#pragma unroll
            for (int j = 0; j < 8; ++j) sh[j * 256 + t] += sh[j * 256 + t + o];
        }
        __syncthreads();
    }
    if (t < 32) {
#pragma unroll
        for (int j = 0; j < 8; ++j)
            partial[blockIdx.x * 256 + j * 32 + t] = sh[j * 256 + t];
    }
}

// K2: reduce partials; fold batchnorm into per-column scale/shift.
// column c: sum at plane j=c&3, slot t=c>>2 ; sq at plane 4+(c&3).
__global__ __launch_bounds__(256) void finalize_kernel(const float* __restrict__ partial,
                                                       const float* __restrict__ gamma,
                                                       const float* __restrict__ beta,
                                                       float* __restrict__ scale,
                                                       float* __restrict__ shift) {
    int t = threadIdx.x;
    float s = 0.f;
    for (int b = 0; b < NSTAT_BLK; ++b) s += partial[b * 256 + t];
    __shared__ float tot[256];
    tot[t] = s;
    __syncthreads();
    if (t < 128) {
        int ti = t >> 2, j = t & 3;
        const float invn = 1.0f / (float)N_ENT;
        float mu = tot[j * 32 + ti] * invn;
        float var = tot[(j + 4) * 32 + ti] * invn - mu * mu;
        float rs = rsqrtf(var + EPS);
        float sc = gamma[t] * rs;
        scale[t] = sc;
        shift[t] = beta[t] - mu * sc;
    }
}

// K3: mark needed nodes (idempotent stores; slot_of pre-filled with -1).
__global__ __launch_bounds__(256) void mark_kernel(const int* __restrict__ neighbor,
                                                   int* __restrict__ slot_of) {
    int b = blockIdx.x * 256 + threadIdx.x;
    if (b < BATCH) slot_of[neighbor[b]] = -2;
}

// K4: assign compact slots to marked nodes — 1 global atomic per block.
__global__ __launch_bounds__(256) void compact_kernel(int* __restrict__ slot_of,
                                                      int* __restrict__ count) {
    int n = blockIdx.x * 256 + threadIdx.x;
    bool marked = (n < N_ENT && slot_of[n] == -2);
    unsigned long long m = __ballot(marked);
    int lane = threadIdx.x & 63;
    int wid = threadIdx.x >> 6;
    int prefix = __popcll(m & ((1ull << lane) - 1ull));
    __shared__ int wsum[4];
    __shared__ int base;
    if (lane == 0) wsum[wid] = __popcll(m);
    __syncthreads();
    if (threadIdx.x == 0) {
        base = atomicAdd(count, wsum[0] + wsum[1] + wsum[2] + wsum[3]);
    }
    __syncthreads();
    int wbase = 0;
    for (int i = 0; i < wid; ++i) wbase += wsum[i];
    if (marked) slot_of[n] = base + wbase + prefix;
}

// K5: single edge pass, int4-vectorized — bucket sources of needed-dst edges.
__global__ __launch_bounds__(256) void edge_bucket_kernel(const int4* __restrict__ src4,
                                                          const int4* __restrict__ dst4,
                                                          const int* __restrict__ slot_of,
                                                          int* __restrict__ bcount,
                                                          int* __restrict__ bucket) {
    const int n4 = N_EDGES / 4;   // 400000, exact
    for (int e = blockIdx.x * blockDim.x + threadIdx.x; e < n4;
         e += gridDim.x * blockDim.x) {
        int4 d = dst4[e];
        int4 s = src4[e];
        int sl0 = slot_of[d.x];
        int sl1 = slot_of[d.y];
        int sl2 = slot_of[d.z];
        int sl3 = slot_of[d.w];
        if (sl0 >= 0) { int p = atomicAdd(&bcount[sl0], 1); if (p < CAP) bucket[sl0 * CAP + p] = s.x; }
        if (sl1 >= 0) { int p = atomicAdd(&bcount[sl1], 1); if (p < CAP) bucket[sl1 * CAP + p] = s.y; }
        if (sl2 >= 0) { int p = atomicAdd(&bcount[sl2], 1); if (p < CAP) bucket[sl2 * CAP + p] = s.z; }
        if (sl3 >= 0) { int p = atomicAdd(&bcount[sl3], 1); if (p < CAP) bucket[sl3 * CAP + p] = s.w; }
    }
}

// K6: gather-aggregate per needed slot. One 64-lane wave per slot.
// hcomp[slot] = (scale * sum(E[src]) + deg*shift) / max(deg,1)
__global__ __launch_bounds__(256) void gather_kernel(const float4* __restrict__ E4,
                                                     const int* __restrict__ count,
                                                     const int* __restrict__ bcount,
                                                     const int* __restrict__ bucket,
                                                     const float4* __restrict__ scale4,
                                                     const float4* __restrict__ shift4,
                                                     float* __restrict__ hcomp) {
    int t = threadIdx.x;
    int slot = blockIdx.x * 4 + (t >> 6);
    int U = count[0];
    if (slot >= U) return;
    int lane = t & 63;
    int q = lane & 31;
    int sub = lane >> 5;
    int dg = bcount[slot];
    int m = dg < CAP ? dg : CAP;
    float ax = 0.f, ay = 0.f, az = 0.f, aw = 0.f;
    for (int i = sub; i < m; i += 2) {
        int s = bucket[slot * CAP + i];
        float4 ev = E4[(size_t)s * 32 + q];
        ax += ev.x; ay += ev.y; az += ev.z; aw += ev.w;
    }
    ax += __shfl_down(ax, 32);
    ay += __shfl_down(ay, 32);
    az += __shfl_down(az, 32);
    aw += __shfl_down(aw, 32);
    if (sub == 0) {
        float fdg = (float)dg;
        float rd = 1.0f / fmaxf(fdg, 1.0f);
        float4 sc = scale4[q];
        float4 sf = shift4[q];
        float4 o;
        o.x = (ax * sc.x + fdg * sf.x) * rd;
        o.y = (ay * sc.y + fdg * sf.y) * rd;
        o.z = (az * sc.z + fdg * sf.z) * rd;
        o.w = (aw * sc.w + fdg * sf.w) * rd;
        ((float4*)(hcomp + (size_t)slot * DIM))[q] = o;
    }
}

// K7: h2 = relu(hcomp @ W + b), in-place. 32 rows/block.
__global__ __launch_bounds__(256) void gnn_gemm_kernel(float* __restrict__ hcomp,
                                                       const float* __restrict__ W,
                                                       const float* __restrict__ bias) {
    __shared__ float A_s[32 * 128];
    int t = threadIdx.x;
    int rowbase = blockIdx.x * 32;

    const float4* src4 = (const float4*)(hcomp + (size_t)rowbase * DIM);
#pragma unroll
    for (int i = 0; i < 4; ++i) {
        int f4 = t + i * 256;
        ((float4*)A_s)[f4] = src4[f4];
    }
    __syncthreads();

    int cg = t & 31;
    int rg = t >> 5;
    int r0 = rg * 4;
    float acc[4][4] = {{0.f}};
    const float4* W4 = (const float4*)W;
#pragma unroll 4
    for (int k = 0; k < 128; ++k) {
        float4 wv = W4[k * 32 + cg];
#pragma unroll
        for (int i = 0; i < 4; ++i) {
            float a = A_s[(r0 + i) * 128 + k];
            acc[i][0] += a * wv.x;
            acc[i][1] += a * wv.y;
            acc[i][2] += a * wv.z;
            acc[i][3] += a * wv.w;
        }
    }
    float4 bv = ((const float4*)bias)[cg];
#pragma unroll
    for (int i = 0; i < 4; ++i) {
        float4 o;
        o.x = fmaxf(acc[i][0] + bv.x, 0.f);
        o.y = fmaxf(acc[i][1] + bv.y, 0.f);
        o.z = fmaxf(acc[i][2] + bv.z, 0.f);
        o.w = fmaxf(acc[i][3] + bv.w, 0.f);
        ((float4*)(hcomp + (size_t)(rowbase + r0 + i) * DIM))[cg] = o;
    }
}

// K8: heads. One 64-thread wave per batch element; u via slot_of indirection.
__global__ __launch_bounds__(64) void heads_kernel(const float* __restrict__ hcomp,
                                                   const int* __restrict__ slot_of,
                                                   const int* __restrict__ neighbor,
                                                   const float* __restrict__ W_g,
                                                   const float* __restrict__ b_g,
                                                   const float* __restrict__ W_age,
                                                   const float* __restrict__ b_age,
                                                   const float* __restrict__ W_occ,
                                                   const float* __restrict__ b_occ,
                                                   float* __restrict__ out_age,
                                                   float* __restrict__ out_gender,
                                                   float* __restrict__ out_occ) {
    int b = blockIdx.x;
    int lane = threadIdx.x;
    int slot = slot_of[neighbor[b]];
    __shared__ float u[DIM];
    ((float2*)u)[lane] = ((const float2*)(hcomp + (size_t)slot * DIM))[lane];
    __syncthreads();
    if (lane < 7) {
        float acc = b_age[lane];
        for (int d = 0; d < DIM; ++d) acc += u[d] * W_age[d * 7 + lane];
        out_age[b * 7 + lane] = acc;
    } else if (lane < 28) {
        int c = lane - 7;
        float acc = b_occ[c];
        for (int d = 0; d < DIM; ++d) acc += u[d] * W_occ[d * 21 + c];
        out_occ[b * 21 + c] = acc;
    } else if (lane == 28) {
        float acc = b_g[0];
        for (int d = 0; d < DIM; ++d) acc += u[d] * W_g[d];
        out_gender[b] = acc;
    }
}

// K9: BCE-with-logits mean.
__global__ __launch_bounds__(256) void loss_kernel(const float* __restrict__ gender_pred,
                                                   const int* __restrict__ gender,
                                                   float* __restrict__ out_loss) {
    int t = threadIdx.x;
    float s = 0.f;
    for (int i = t; i < BATCH; i += 256) {
        float x = gender_pred[i];
        float z = (float)gender[i];
        s += fmaxf(x, 0.f) - x * z + log1pf(expf(-fabsf(x)));
    }
    __shared__ float sh[256];
    sh[t] = s;
    __syncthreads();
    for (int o = 128; o > 0; o >>= 1) {
        if (t < o) sh[t] += sh[t + o];
        __syncthreads();
    }
    if (t == 0) out_loss[0] = sh[0] / (float)BATCH;
}

extern "C" void kernel_launch(void* const* d_in, const int* in_sizes, int n_in,
                              void* d_out, int out_size, void* d_ws, size_t ws_size,
                              hipStream_t stream) {
    const float* E      = (const float*)d_in[0];
    const float* gamma  = (const float*)d_in[1];
    const float* beta   = (const float*)d_in[2];
    const float* W_gnn  = (const float*)d_in[3];
    const float* b_gnn  = (const float*)d_in[4];
    const float* W_g    = (const float*)d_in[5];
    const float* b_g    = (const float*)d_in[6];
    const float* W_age  = (const float*)d_in[7];
    const float* b_age  = (const float*)d_in[8];
    const float* W_occ  = (const float*)d_in[9];
    const float* b_occ  = (const float*)d_in[10];
    const int*   src    = (const int*)d_in[11];
    const int*   dst    = (const int*)d_in[12];
    const int*   neigh  = (const int*)d_in[13];
    const int*   gender = (const int*)d_in[14];

    float* ws       = (float*)d_ws;
    int*   wsi      = (int*)d_ws;
    float* scale    = ws + WS_SCALE;
    float* shift    = ws + WS_SHIFT;
    int*   count    = wsi + WS_COUNT;
    int*   bcount   = wsi + WS_BCOUNT;
    int*   slot_of  = wsi + WS_SLOTOF;
    int*   bucket   = wsi + WS_BUCKET;
    float* hcomp    = ws + WS_HCOMP;
    float* partial  = ws + WS_PARTIAL;

    float* out       = (float*)d_out;
    float* out_loss  = out;                         // [1]
    float* out_age   = out + 1;                     // [8192,7]
    float* out_gen   = out + 1 + BATCH * 7;         // [8192]
    float* out_occ   = out + 1 + BATCH * 7 + BATCH; // [8192,21]

    // init: zeros for count/bcount, 0xFF (-1) for slot_of
    hipMemsetAsync(d_ws, 0, (size_t)WS_ZERO_INTS * 4, stream);
    hipMemsetAsync((void*)slot_of, 0xFF, (size_t)N_ENT * 4, stream);

    stats_kernel<<<NSTAT_BLK, 256, 0, stream>>>((const float4*)E, partial);
    finalize_kernel<<<1, 256, 0, stream>>>(partial, gamma, beta, scale, shift);
    mark_kernel<<<BATCH / 256, 256, 0, stream>>>(neigh, slot_of);
    compact_kernel<<<(N_ENT + 255) / 256, 256, 0, stream>>>(slot_of, count);
    edge_bucket_kernel<<<1024, 256, 0, stream>>>((const int4*)src, (const int4*)dst,
                                                 slot_of, bcount, bucket);
    gather_kernel<<<BATCH / 4, 256, 0, stream>>>((const float4*)E, count, bcount, bucket,
                                                 (const float4*)scale, (const float4*)shift,
                                                 hcomp);
    gnn_gemm_kernel<<<BATCH / 32, 256, 0, stream>>>(hcomp, W_gnn, b_gnn);
    heads_kernel<<<BATCH, 64, 0, stream>>>(hcomp, slot_of, neigh, W_g, b_g,
                                           W_age, b_age, W_occ, b_occ,
                                           out_age, out_gen, out_occ);
    loss_kernel<<<1, 256, 0, stream>>>(out_gen, gender, out_loss);
}

// Round 6
// 210.482 us; speedup vs baseline: 1.5586x; 1.1139x over previous
//
#include <hip/hip_runtime.h>
#include <hip/hip_bf16.h>
#include <math.h>

#define N_ENT   100000
#define DIM     128
#define N_EDGES 1600000
#define BATCH   8192
#define EPS     1e-5f
#define CAP     128          // max neighbors stored per needed node (Poisson(16) tail ~0)
#define NSTAT_BLK 512

// ---------------- ws layout (4-byte elements) ----------------
#define WS_SCALE     256        // f[128]
#define WS_SHIFT     384        // f[128]
#define WS_COUNT     512        // i[16] (count in [0])
#define WS_BCOUNT    528        // i[8192] per-slot edge count (== degree)
#define WS_SLOTOF    8720       // i[100000]  (-1 = unneeded, -2 = marked, >=0 = slot)
#define WS_BUCKET    108720     // i[8192*128]   (16B aligned)
#define WS_SLOTHEAD  1157296    // f[8192*32]    per-slot head logits (age 0-6, occ 7-27, gender 28)
#define WS_PARTIAL   1419440    // f[512*256]    stats partials

// K0: init all state the pipeline needs (ws is poisoned 0xAA before every launch).
__global__ __launch_bounds__(256) void init_kernel(int* __restrict__ slot_of,
                                                   int* __restrict__ bcount,
                                                   int* __restrict__ count,
                                                   float* __restrict__ out_loss) {
    int n = blockIdx.x * 256 + threadIdx.x;
    if (n < N_ENT) slot_of[n] = -1;
    if (n < BATCH) bcount[n] = 0;
    if (n < 16)    count[n] = 0;
    if (n == 0)    out_loss[0] = 0.f;
}

// K1: per-column sum/sumsq of E, float4 lanes, x4-unrolled rows, NO atomics.
__global__ __launch_bounds__(256) void stats_kernel(const float4* __restrict__ E4,
                                                    float* __restrict__ partial) {
    int t = threadIdx.x;
    int cg = t & 31;
    int rs = t >> 5;
    const int STRIDE = NSTAT_BLK * 8;   // 4096 rows per sweep
    float sx = 0.f, sy = 0.f, sz = 0.f, sw = 0.f;
    float qx = 0.f, qy = 0.f, qz = 0.f, qw = 0.f;
    const float4 z4 = make_float4(0.f, 0.f, 0.f, 0.f);
    for (int r = blockIdx.x * 8 + rs; r < N_ENT; r += 4 * STRIDE) {
        int r1 = r + STRIDE, r2 = r + 2 * STRIDE, r3 = r + 3 * STRIDE;
        float4 v0 = E4[(size_t)r * 32 + cg];
        float4 v1 = (r1 < N_ENT) ? E4[(size_t)r1 * 32 + cg] : z4;
        float4 v2 = (r2 < N_ENT) ? E4[(size_t)r2 * 32 + cg] : z4;
        float4 v3 = (r3 < N_ENT) ? E4[(size_t)r3 * 32 + cg] : z4;
        sx += v0.x + v1.x + v2.x + v3.x;
        sy += v0.y + v1.y + v2.y + v3.y;
        sz += v0.z + v1.z + v2.z + v3.z;
        sw += v0.w + v1.w + v2.w + v3.w;
        qx += v0.x * v0.x + v1.x * v1.x + v2.x * v2.x + v3.x * v3.x;
        qy += v0.y * v0.y + v1.y * v1.y + v2.y * v2.y + v3.y * v3.y;
        qz += v0.z * v0.z + v1.z * v1.z + v2.z * v2.z + v3.z * v3.z;
        qw += v0.w * v0.w + v1.w * v1.w + v2.w * v2.w + v3.w * v3.w;
    }
    __shared__ float sh[8 * 256];
    sh[0 * 256 + t] = sx; sh[1 * 256 + t] = sy;
    sh[2 * 256 + t] = sz; sh[3 * 256 + t] = sw;
    sh[4 * 256 + t] = qx; sh[5 * 256 + t] = qy;
    sh[6 * 256 + t] = qz; sh[7 * 256 + t] = qw;
    __syncthreads();
    for (int o = 128; o >= 32; o >>= 1) {
        if (t < o) {
#pragma unroll
            for (int j = 0; j < 8; ++j) sh[j * 256 + t] += sh[j * 256 + t + o];
        }
        __syncthreads();
    }
    if (t < 32) {
#pragma unroll
        for (int j = 0; j < 8; ++j)
            partial[blockIdx.x * 256 + j * 32 + t] = sh[j * 256 + t];
    }
}

// K2: reduce partials; fold batchnorm into per-column scale/shift.
__global__ __launch_bounds__(256) void finalize_kernel(const float* __restrict__ partial,
                                                       const float* __restrict__ gamma,
                                                       const float* __restrict__ beta,
                                                       float* __restrict__ scale,
                                                       float* __restrict__ shift) {
    int t = threadIdx.x;
    float s = 0.f;
    for (int b = 0; b < NSTAT_BLK; ++b) s += partial[b * 256 + t];
    __shared__ float tot[256];
    tot[t] = s;
    __syncthreads();
    if (t < 128) {
        int ti = t >> 2, j = t & 3;
        const float invn = 1.0f / (float)N_ENT;
        float mu = tot[j * 32 + ti] * invn;
        float var = tot[(j + 4) * 32 + ti] * invn - mu * mu;
        float rs = rsqrtf(var + EPS);
        float sc = gamma[t] * rs;
        scale[t] = sc;
        shift[t] = beta[t] - mu * sc;
    }
}

// K3: mark needed nodes (idempotent stores; slot_of pre-filled with -1).
__global__ __launch_bounds__(256) void mark_kernel(const int* __restrict__ neighbor,
                                                   int* __restrict__ slot_of) {
    int b = blockIdx.x * 256 + threadIdx.x;
    if (b < BATCH) slot_of[neighbor[b]] = -2;
}

// K4: assign compact slots to marked nodes — 1 global atomic per block.
__global__ __launch_bounds__(256) void compact_kernel(int* __restrict__ slot_of,
                                                      int* __restrict__ count) {
    int n = blockIdx.x * 256 + threadIdx.x;
    bool marked = (n < N_ENT && slot_of[n] == -2);
    unsigned long long m = __ballot(marked);
    int lane = threadIdx.x & 63;
    int wid = threadIdx.x >> 6;
    int prefix = __popcll(m & ((1ull << lane) - 1ull));
    __shared__ int wsum[4];
    __shared__ int base;
    if (lane == 0) wsum[wid] = __popcll(m);
    __syncthreads();
    if (threadIdx.x == 0) {
        base = atomicAdd(count, wsum[0] + wsum[1] + wsum[2] + wsum[3]);
    }
    __syncthreads();
    int wbase = 0;
    for (int i = 0; i < wid; ++i) wbase += wsum[i];
    if (marked) slot_of[n] = base + wbase + prefix;
}

// K5: single edge pass, int4-vectorized — bucket sources of needed-dst edges.
__global__ __launch_bounds__(256) void edge_bucket_kernel(const int4* __restrict__ src4,
                                                          const int4* __restrict__ dst4,
                                                          const int* __restrict__ slot_of,
                                                          int* __restrict__ bcount,
                                                          int* __restrict__ bucket) {
    const int n4 = N_EDGES / 4;   // 400000, exact
    for (int e = blockIdx.x * blockDim.x + threadIdx.x; e < n4;
         e += gridDim.x * blockDim.x) {
        int4 d = dst4[e];
        int4 s = src4[e];
        int sl0 = slot_of[d.x];
        int sl1 = slot_of[d.y];
        int sl2 = slot_of[d.z];
        int sl3 = slot_of[d.w];
        if (sl0 >= 0) { int p = atomicAdd(&bcount[sl0], 1); if (p < CAP) bucket[sl0 * CAP + p] = s.x; }
        if (sl1 >= 0) { int p = atomicAdd(&bcount[sl1], 1); if (p < CAP) bucket[sl1 * CAP + p] = s.y; }
        if (sl2 >= 0) { int p = atomicAdd(&bcount[sl2], 1); if (p < CAP) bucket[sl2 * CAP + p] = s.z; }
        if (sl3 >= 0) { int p = atomicAdd(&bcount[sl3], 1); if (p < CAP) bucket[sl3 * CAP + p] = s.w; }
    }
}

// K6: FUSED per-slot pipeline. One 64-lane wave per slot:
//  (a) gather-sum neighbor E rows (4 rows in flight: sub-split x 2-unroll)
//  (b) normalize -> h row in wave-local LDS
//  (c) 1x128 @ 128x128 GEMM + bias + relu -> h2 back into LDS
//  (d) 29 head logits (age7/occ21/gender1) -> slot_heads
// No early return (guarded by pred) so __syncthreads is uniform.
__global__ __launch_bounds__(256) void gather_gemm_heads_kernel(
        const float4* __restrict__ E4,
        const int* __restrict__ count,
        const int* __restrict__ bcount,
        const int* __restrict__ bucket,
        const float4* __restrict__ scale4,
        const float4* __restrict__ shift4,
        const float4* __restrict__ W4,
        const float4* __restrict__ bias4,
        const float* __restrict__ W_g,
        const float* __restrict__ b_g,
        const float* __restrict__ W_age,
        const float* __restrict__ b_age,
        const float* __restrict__ W_occ,
        const float* __restrict__ b_occ,
        float* __restrict__ slot_heads) {
    __shared__ float hrow[4][128];
    int t = threadIdx.x;
    int wv = t >> 6;
    int slot = blockIdx.x * 4 + wv;
    int U = count[0];
    bool pred = (slot < U);
    int lane = t & 63;
    int q = lane & 31;
    int sub = lane >> 5;
    int dg = pred ? bcount[slot] : 0;
    int m = dg < CAP ? dg : CAP;
    const int* bk = bucket + slot * CAP;

    // (a) gather: sub handles rows {sub, sub+2, ...}; 2x unroll -> 4 rows in flight
    float ax = 0.f, ay = 0.f, az = 0.f, aw = 0.f;
    int i = sub;
    for (; i + 2 < m; i += 4) {
        int s0 = bk[i], s1 = bk[i + 2];
        float4 v0 = E4[(size_t)s0 * 32 + q];
        float4 v1 = E4[(size_t)s1 * 32 + q];
        ax += v0.x + v1.x; ay += v0.y + v1.y;
        az += v0.z + v1.z; aw += v0.w + v1.w;
    }
    for (; i < m; i += 2) {
        int s0 = bk[i];
        float4 v0 = E4[(size_t)s0 * 32 + q];
        ax += v0.x; ay += v0.y; az += v0.z; aw += v0.w;
    }
    ax += __shfl_down(ax, 32);
    ay += __shfl_down(ay, 32);
    az += __shfl_down(az, 32);
    aw += __shfl_down(aw, 32);
    // (b) normalize + stage to LDS
    if (sub == 0) {
        float fdg = (float)dg;
        float rd = 1.0f / fmaxf(fdg, 1.0f);
        float4 sc = scale4[q];
        float4 sf = shift4[q];
        float4 o;
        o.x = (ax * sc.x + fdg * sf.x) * rd;
        o.y = (ay * sc.y + fdg * sf.y) * rd;
        o.z = (az * sc.z + fdg * sf.z) * rd;
        o.w = (aw * sc.w + fdg * sf.w) * rd;
        ((float4*)hrow[wv])[q] = o;
    }
    __syncthreads();
    // (c) GEMM: lane computes cols [4q,4q+4) over k in [64*sub, 64*sub+64)
    float cx = 0.f, cy = 0.f, cz = 0.f, cw = 0.f;
    int k0 = sub * 64;
#pragma unroll 4
    for (int kk = 0; kk < 64; ++kk) {
        float a = hrow[wv][k0 + kk];
        float4 w = W4[(size_t)(k0 + kk) * 32 + q];
        cx += a * w.x; cy += a * w.y; cz += a * w.z; cw += a * w.w;
    }
    cx += __shfl_down(cx, 32);
    cy += __shfl_down(cy, 32);
    cz += __shfl_down(cz, 32);
    cw += __shfl_down(cw, 32);
    __syncthreads();   // all hrow reads done before overwrite
    if (sub == 0) {
        float4 bv = bias4[q];
        float4 h2;
        h2.x = fmaxf(cx + bv.x, 0.f);
        h2.y = fmaxf(cy + bv.y, 0.f);
        h2.z = fmaxf(cz + bv.z, 0.f);
        h2.w = fmaxf(cw + bv.w, 0.f);
        ((float4*)hrow[wv])[q] = h2;
    }
    __syncthreads();
    // (d) heads: 29 lanes, one logit each; uniform loop, per-lane weight ptr
    if (pred && lane < 29) {
        const float* Wp;
        int stride;
        float acch;
        if (lane < 7)       { Wp = W_age + lane;      stride = 7;  acch = b_age[lane]; }
        else if (lane < 28) { Wp = W_occ + (lane - 7); stride = 21; acch = b_occ[lane - 7]; }
        else                { Wp = W_g;               stride = 1;  acch = b_g[0]; }
#pragma unroll 4
        for (int d = 0; d < DIM; ++d) acch += hrow[wv][d] * Wp[d * stride];
        slot_heads[slot * 32 + lane] = acch;
    }
}

// K7: map per-slot head logits to batch outputs + fused BCE loss.
__global__ __launch_bounds__(256) void map_loss_kernel(const float* __restrict__ slot_heads,
                                                       const int* __restrict__ slot_of,
                                                       const int* __restrict__ neighbor,
                                                       const int* __restrict__ gender,
                                                       float* __restrict__ out_age,
                                                       float* __restrict__ out_gender,
                                                       float* __restrict__ out_occ,
                                                       float* __restrict__ out_loss) {
    int b = blockIdx.x * 256 + threadIdx.x;
    float val = 0.f;
    if (b < BATCH) {
        int slot = slot_of[neighbor[b]];
        const float* hs = slot_heads + (size_t)slot * 32;
#pragma unroll
        for (int c = 0; c < 7; ++c)  out_age[b * 7 + c] = hs[c];
#pragma unroll
        for (int c = 0; c < 21; ++c) out_occ[b * 21 + c] = hs[7 + c];
        float x = hs[28];
        out_gender[b] = x;
        float z = (float)gender[b];
        val = fmaxf(x, 0.f) - x * z + log1pf(expf(-fabsf(x)));
    }
    __shared__ float sh[256];
    sh[threadIdx.x] = val;
    __syncthreads();
    for (int o = 128; o > 0; o >>= 1) {
        if (threadIdx.x < o) sh[threadIdx.x] += sh[threadIdx.x + o];
        __syncthreads();
    }
    if (threadIdx.x == 0) atomicAdd(out_loss, sh[0] * (1.0f / (float)BATCH));
}

extern "C" void kernel_launch(void* const* d_in, const int* in_sizes, int n_in,
                              void* d_out, int out_size, void* d_ws, size_t ws_size,
                              hipStream_t stream) {
    const float* E      = (const float*)d_in[0];
    const float* gamma  = (const float*)d_in[1];
    const float* beta   = (const float*)d_in[2];
    const float* W_gnn  = (const float*)d_in[3];
    const float* b_gnn  = (const float*)d_in[4];
    const float* W_g    = (const float*)d_in[5];
    const float* b_g    = (const float*)d_in[6];
    const float* W_age  = (const float*)d_in[7];
    const float* b_age  = (const float*)d_in[8];
    const float* W_occ  = (const float*)d_in[9];
    const float* b_occ  = (const float*)d_in[10];
    const int*   src    = (const int*)d_in[11];
    const int*   dst    = (const int*)d_in[12];
    const int*   neigh  = (const int*)d_in[13];
    const int*   gender = (const int*)d_in[14];

    float* ws        = (float*)d_ws;
    int*   wsi       = (int*)d_ws;
    float* scale     = ws + WS_SCALE;
    float* shift     = ws + WS_SHIFT;
    int*   count     = wsi + WS_COUNT;
    int*   bcount    = wsi + WS_BCOUNT;
    int*   slot_of   = wsi + WS_SLOTOF;
    int*   bucket    = wsi + WS_BUCKET;
    float* slot_hd   = ws + WS_SLOTHEAD;
    float* partial   = ws + WS_PARTIAL;

    float* out       = (float*)d_out;
    float* out_loss  = out;                         // [1]
    float* out_age   = out + 1;                     // [8192,7]
    float* out_gen   = out + 1 + BATCH * 7;         // [8192]
    float* out_occ   = out + 1 + BATCH * 7 + BATCH; // [8192,21]

    init_kernel<<<(N_ENT + 255) / 256, 256, 0, stream>>>(slot_of, bcount, count, out_loss);
    stats_kernel<<<NSTAT_BLK, 256, 0, stream>>>((const float4*)E, partial);
    finalize_kernel<<<1, 256, 0, stream>>>(partial, gamma, beta, scale, shift);
    mark_kernel<<<BATCH / 256, 256, 0, stream>>>(neigh, slot_of);
    compact_kernel<<<(N_ENT + 255) / 256, 256, 0, stream>>>(slot_of, count);
    edge_bucket_kernel<<<1024, 256, 0, stream>>>((const int4*)src, (const int4*)dst,
                                                 slot_of, bcount, bucket);
    gather_gemm_heads_kernel<<<BATCH / 4, 256, 0, stream>>>(
        (const float4*)E, count, bcount, bucket,
        (const float4*)scale, (const float4*)shift,
        (const float4*)W_gnn, (const float4*)b_gnn,
        W_g, b_g, W_age, b_age, W_occ, b_occ, slot_hd);
    map_loss_kernel<<<BATCH / 256, 256, 0, stream>>>(slot_hd, slot_of, neigh, gender,
                                                     out_age, out_gen, out_occ, out_loss);
}